// Round 2
// baseline (231.292 us; speedup 1.0000x reference)
//
#include <hip/hip_runtime.h>

#define ALPHA 0.90483741803595957f

// ---------------------------------------------------------------------------
// K0: fold avgpool into conv kernels.
// W1eff[oc][ch][u][v] (4x2x8x8): conv1 5x5 pad2 + pool4  => 8x8 stride-4 conv
// W2eff[oc][ch][u][v] (8x4x4x4): conv2 3x3 pad1 + pool2  => 4x4 stride-2 conv
// ---------------------------------------------------------------------------
__global__ void prep_weights(const float* __restrict__ w1, const float* __restrict__ w2,
                             float* __restrict__ w1e, float* __restrict__ w2e) {
    int idx = blockIdx.x * 256 + threadIdx.x;
    if (idx < 512) {
        int v = idx & 7, u = (idx >> 3) & 7, ch = (idx >> 6) & 1, oc = idx >> 7;
        float s = 0.f;
        for (int a = 0; a < 5; ++a) {
            int i = u - a; if (i < 0 || i > 3) continue;
            for (int b = 0; b < 5; ++b) {
                int j = v - b; if (j < 0 || j > 3) continue;
                s += w1[((oc * 2 + ch) * 5 + a) * 5 + b];
            }
        }
        w1e[idx] = s * (1.f / 16.f);
    } else if (idx < 1024) {
        int k = idx - 512;
        int v = k & 3, u = (k >> 2) & 3, ch = (k >> 4) & 3, oc = k >> 6;
        float s = 0.f;
        for (int a = 0; a < 3; ++a) {
            int i = u - a; if (i < 0 || i > 1) continue;
            for (int b = 0; b < 3; ++b) {
                int j = v - b; if (j < 0 || j > 1) continue;
                s += w2[((oc * 4 + ch) * 3 + a) * 3 + b];
            }
        }
        w2e[k] = s * 0.25f;
    }
}

// ---------------------------------------------------------------------------
// K1: conv1 + pool4 via 8x8/stride-4 effective kernel. (unchanged from R0)
// 4 images per block (1 wave per image). Padded LDS tile 2ch x 36x36 per image.
// ---------------------------------------------------------------------------
__global__ __launch_bounds__(256) void conv1_pool(const float* __restrict__ x,
                                                  const float* __restrict__ w1e,
                                                  float* __restrict__ y1) {
    __shared__ __align__(16) float tile[4][2][36][36];  // 41472 B
    int tid = threadIdx.x;

    float4* t4 = (float4*)&tile[0][0][0][0];
    #pragma unroll
    for (int k = 0; k < 11; ++k) {
        int i = tid + k * 256;
        if (i < 2592) t4[i] = make_float4(0.f, 0.f, 0.f, 0.f);
    }
    __syncthreads();

    int li = tid >> 6, pos = tid & 63;
    long gi = (long)blockIdx.x * 4 + li;            // bt index, < 12800
    const float* src = x + gi * 2048;               // 2ch*32*32
    #pragma unroll
    for (int k = 0; k < 8; ++k) {
        int e = k * 256 + pos * 4;                  // 16B-aligned
        float4 d = *(const float4*)(src + e);
        int ch = e >> 10, rem = e & 1023, r = rem >> 5, c = rem & 31;
        float* dst = &tile[li][ch][r + 2][c + 2];
        dst[0] = d.x; dst[1] = d.y; dst[2] = d.z; dst[3] = d.w;
    }
    __syncthreads();

    int p = pos >> 3, q = pos & 7;
    float acc0 = 0.f, acc1 = 0.f, acc2 = 0.f, acc3 = 0.f;
    #pragma unroll
    for (int ch = 0; ch < 2; ++ch) {
        #pragma unroll
        for (int r = 0; r < 8; ++r) {
            const float* row = &tile[li][ch][4 * p + r][4 * q];  // 16B aligned
            float4 a = *(const float4*)row;
            float4 b = *(const float4*)(row + 4);
            float in[8] = {a.x, a.y, a.z, a.w, b.x, b.y, b.z, b.w};
            #pragma unroll
            for (int c = 0; c < 8; ++c) {
                float xi = in[c];
                acc0 += w1e[((0 * 2 + ch) * 8 + r) * 8 + c] * xi;  // uniform -> s_load
                acc1 += w1e[((1 * 2 + ch) * 8 + r) * 8 + c] * xi;
                acc2 += w1e[((2 * 2 + ch) * 8 + r) * 8 + c] * xi;
                acc3 += w1e[((3 * 2 + ch) * 8 + r) * 8 + c] * xi;
            }
        }
    }
    float* dst = y1 + gi * 256 + pos;   // [bt][oc][p][q], f = oc*64 + p*8 + q
    dst[0] = acc0; dst[64] = acc1; dst[128] = acc2; dst[192] = acc3;
}

// ---------------------------------------------------------------------------
// K2: FUSED scan1 + conv2+pool2 + scan2 + linear. One block per b.
// Per t: all 256 threads do stage-1 LIF -> spike tile in LDS;
//        waves 0-1 (f<128): conv2 (register weights) + stage-2 LIF -> s2buf;
//        waves 2-3: reduce PREVIOUS t's s2 with linear weights (shuffle).
// 2 barriers per t. Output collected in LDS, dumped coalesced at the end.
// ---------------------------------------------------------------------------
__global__ __launch_bounds__(256) void fused_rest(const float* __restrict__ y1,
                                                  const float* __restrict__ w2e,
                                                  const float* __restrict__ lw,
                                                  float* __restrict__ out) {
    __shared__ __align__(16) float spk[4][10][10];   // padded spike tile (400 f)
    __shared__ __align__(16) float s2buf[2][128];    // double-buffered stage-2 spikes
    __shared__ __align__(16) float outbuf[100][2];
    int tid = threadIdx.x;
    int b = blockIdx.x;

    // zero spk (pad borders stay zero forever; interior overwritten each t)
    for (int i = tid; i < 400; i += 256) ((float*)spk)[i] = 0.f;

    // conv2 effective weights -> registers (threads g<128, one oc each)
    float wreg[64];
    int g = tid, oc = g >> 4, p = (g >> 2) & 3, q = g & 3;
    if (tid < 128) {
        const float4* wsrc = (const float4*)(w2e + oc * 64);
        #pragma unroll
        for (int k = 0; k < 16; ++k) {
            float4 w = wsrc[k];
            wreg[4 * k] = w.x; wreg[4 * k + 1] = w.y;
            wreg[4 * k + 2] = w.z; wreg[4 * k + 3] = w.w;
        }
    }
    // linear weights for the reducer waves
    int lane = tid & 63;
    float lwa = 0.f, lwb = 0.f;
    if (tid >= 128) {
        int o = (tid >> 6) - 2;
        float2 lv = *(const float2*)(lw + o * 128 + 2 * lane);
        lwa = lv.x; lwb = lv.y;
    }

    const float* yp = y1 + (long)b * 25600 + tid;
    float v1a = 0.f, v1b = 0.f, v2a = 0.f, v2b = 0.f;
    int ch = tid >> 6, r = (tid >> 3) & 7, c = tid & 7;

    float xt = yp[0];
    __syncthreads();   // spk zeros visible

    for (int t = 0; t < 100; ++t) {
        float xn = (t < 99) ? yp[(t + 1) * 256] : 0.f;   // prefetch next t
        // phase A: stage-1 exp_leak + LIF (all 256 features)
        v1a = ALPHA * v1a + xt;
        v1b = ALPHA * v1b + v1a;
        float s = (v1b >= 1.f) ? 1.f : 0.f;
        v1b -= s;
        spk[ch][r + 1][c + 1] = s;
        xt = xn;
        __syncthreads();
        // phase B
        if (tid < 128) {
            float acc = 0.f;
            #pragma unroll
            for (int cc = 0; cc < 4; ++cc) {
                #pragma unroll
                for (int rr = 0; rr < 4; ++rr) {
                    const float* rowp = &spk[cc][2 * p + rr][2 * q];  // 8B aligned
                    float2 a = *(const float2*)rowp;
                    float2 bb = *(const float2*)(rowp + 2);
                    int wb = cc * 16 + rr * 4;
                    acc += wreg[wb] * a.x + wreg[wb + 1] * a.y
                         + wreg[wb + 2] * bb.x + wreg[wb + 3] * bb.y;
                }
            }
            v2a = ALPHA * v2a + acc;
            v2b = ALPHA * v2b + v2a;
            float s2 = (v2b >= 1.f) ? 1.f : 0.f;
            v2b -= s2;
            s2buf[t & 1][g] = s2;
        } else if (t > 0) {
            float2 sv = *(const float2*)&s2buf[(t - 1) & 1][2 * lane];
            float pa = sv.x * lwa + sv.y * lwb;
            #pragma unroll
            for (int off = 32; off; off >>= 1) pa += __shfl_down(pa, off);
            if (lane == 0) outbuf[t - 1][(tid >> 6) - 2] = pa;
        }
        __syncthreads();
    }
    // final reduce for t=99
    if (tid >= 128) {
        float2 sv = *(const float2*)&s2buf[1][2 * lane];
        float pa = sv.x * lwa + sv.y * lwb;
        #pragma unroll
        for (int off = 32; off; off >>= 1) pa += __shfl_down(pa, off);
        if (lane == 0) outbuf[99][(tid >> 6) - 2] = pa;
    }
    __syncthreads();
    float* op = out + (long)b * 200;
    if (tid < 200) op[tid] = ((float*)outbuf)[tid];
}

extern "C" void kernel_launch(void* const* d_in, const int* in_sizes, int n_in,
                              void* d_out, int out_size, void* d_ws, size_t ws_size,
                              hipStream_t stream) {
    const float* x  = (const float*)d_in[0];   // [128,100,2,32,32]
    const float* w1 = (const float*)d_in[1];   // [4,2,5,5]
    const float* w2 = (const float*)d_in[2];   // [8,4,3,3]
    const float* lw = (const float*)d_in[3];   // [2,128]
    float* out = (float*)d_out;                // [128,100,2]

    float* ws  = (float*)d_ws;
    float* w1e = ws;                 // 512 floats
    float* w2e = ws + 512;           // 512 floats
    float* y1  = ws + 1024;          // 12800*256 floats = 13.1 MB

    prep_weights<<<4, 256, 0, stream>>>(w1, w2, w1e, w2e);
    conv1_pool<<<3200, 256, 0, stream>>>(x, w1e, y1);
    fused_rest<<<128, 256, 0, stream>>>(y1, w2e, lw, out);
}